// Round 1
// 593.491 us; speedup vs baseline: 1.0976x; 1.0976x over previous
//
#include <hip/hip_runtime.h>
#include <stdint.h>

#define Bn   2048
#define Nn   20
#define Dn   512
#define Hn   8
#define Mn   (Bn*Nn)      // 40960 rows
#define K3n  1536
#define NPn  22           // padded sequence rows
#define BKn  32

typedef __attribute__((ext_vector_type(4))) float  floatx4;
typedef __attribute__((ext_vector_type(8))) __bf16 bf16x8;
typedef __attribute__((ext_vector_type(4))) __bf16 bf16x4;

// -------- async global->LDS, 16B per lane; LDS base must be wave-uniform ----
__device__ __forceinline__ void gload_lds16(const void* g, void* l) {
  __builtin_amdgcn_global_load_lds(
      (const __attribute__((address_space(1))) void*)g,
      (__attribute__((address_space(3))) void*)l, 16, 0, 0);
}

// ============================ prep kernels ==================================
// Xpad[b][0]=0, Xpad[b][n]=bf16(x[b][n-1]), Xpad[b][21]=0
__global__ void k_prep_xpad(const float* __restrict__ x, __bf16* __restrict__ xpad) {
  int idx = blockIdx.x * 256 + threadIdx.x;      // over B*22*64 chunks of 8
  int d8 = idx & 63;
  int t  = idx >> 6;                              // b*22 + n
  if (t >= Bn * NPn) return;
  int n = t % NPn;
  int b = t / NPn;
  bf16x8 v;
  if (n == 0 || n == NPn - 1) {
#pragma unroll
    for (int e = 0; e < 8; ++e) v[e] = (__bf16)0.f;
  } else {
    const float4 x0 = *(const float4*)(x + (size_t)((b * Nn + n - 1) * Dn) + d8 * 8);
    const float4 x1 = *(const float4*)(x + (size_t)((b * Nn + n - 1) * Dn) + d8 * 8 + 4);
    v[0] = (__bf16)x0.x; v[1] = (__bf16)x0.y; v[2] = (__bf16)x0.z; v[3] = (__bf16)x0.w;
    v[4] = (__bf16)x1.x; v[5] = (__bf16)x1.y; v[6] = (__bf16)x1.z; v[7] = (__bf16)x1.w;
  }
  *(bf16x8*)(xpad + (size_t)t * Dn + d8 * 8) = v;
}

// WcT[j][kk]: j = seg*512+o (q|k|v), kk = kker*512+i ; = Wseg[o][i][kker]
__global__ void k_prep_wct(const float* __restrict__ Wq, const float* __restrict__ Wk,
                           const float* __restrict__ Wv, __bf16* __restrict__ wct) {
  int idx = blockIdx.x * 256 + threadIdx.x;
  if (idx >= K3n * K3n) return;
  int kk = idx % K3n;
  int j  = idx / K3n;
  int seg = j >> 9, o = j & 511;
  int kker = kk >> 9, i = kk & 511;
  const float* W = (seg == 0) ? Wq : ((seg == 1) ? Wk : Wv);
  wct[idx] = (__bf16)W[(o * 512 + i) * 3 + kker];
}

// WoT[c][k] = Wo[k][c]
__global__ void k_prep_wot(const float* __restrict__ Wo, __bf16* __restrict__ wot) {
  int idx = blockIdx.x * 256 + threadIdx.x;
  if (idx >= Dn * Dn) return;
  int k = idx & 511, c = idx >> 9;
  wot[idx] = (__bf16)Wo[k * Dn + c];
}

// WqfT[dq][d] = Wqf[d][dq]
__global__ void k_prep_wqft(const float* __restrict__ Wqf, __bf16* __restrict__ wqft) {
  int idx = blockIdx.x * 256 + threadIdx.x;
  if (idx >= Dn * 64) return;
  int d = idx & 511, dq = idx >> 9;
  wqft[idx] = (__bf16)Wqf[d * 64 + dq];
}

// bias[h][i][j] = rel_table[i-j+19][h] + alpha*gsb[h][i][j] + bqp[h]
__global__ void k_bias(const float* __restrict__ rel, const float* __restrict__ gsb,
                       const float* __restrict__ alpha, const float* __restrict__ bqp,
                       float* __restrict__ bias) {
  int idx = blockIdx.x * 256 + threadIdx.x;
  if (idx >= Hn * Nn * Nn) return;
  int j = idx % Nn;
  int i = (idx / Nn) % Nn;
  int h = idx / (Nn * Nn);
  bias[idx] = rel[(i - j + Nn - 1) * Hn + h] + alpha[0] * gsb[idx] + bqp[h];
}

// ================= QKV conv-GEMM + LayerNorm + residual =====================
// v2: 128x512 tile (full segment width keeps LN fused), BK=32, 512 thr =
// 8 waves (2 row x 4 col), wave tile 64x128 = 4x8 frags of 16x16x32 bf16
// MFMA -> 32 MFMA/step/wave. TRIPLE-buffered LDS (3 x 40 KB) with 2-step
// prefetch and COUNTED s_waitcnt vmcnt(5) (never 0 in the main loop): the
// stage for step t+2 is issued at step t, so global latency is covered by
// two full compute steps; the per-step s_barrier carries no vmem drain
// (T3/T4). lgkmcnt(0) is pinned before the barrier so no pending ds_read
// can observe the next overwrite. T5 setprio wraps the MFMA cluster.
// LDS chunk swizzle: slot = koct ^ ((row>>1)&3) -> 2-way (free) ds_reads,
// staged via pre-swizzled global source (gload_lds dest must be linear).
// Grid: 960 blocks swizzled so all 3 segs of one m-tile run adjacently on
// the same XCD (A-tile L2-hot for 2/3 of A traffic).
__global__ __launch_bounds__(512, 2)
void k_qkv(const __bf16* __restrict__ xpad, const __bf16* __restrict__ wct,
           const float* __restrict__ gq_g, const float* __restrict__ gq_b,
           const float* __restrict__ gk_g, const float* __restrict__ gk_b,
           const float* __restrict__ gv_g, const float* __restrict__ gv_b,
           __bf16* __restrict__ qkv) {
  __shared__ __bf16 lds[3 * 20480];   // 3 x (A 128x32 + B 512x32) = 120 KB
  __shared__ float red1[512];
  __shared__ float red2[512];

  const int tid  = threadIdx.x;
  const int wave = tid >> 6;
  const int lane = tid & 63;
  const int quad = lane >> 4;
  const int l15  = lane & 15;
  const int rowg = wave >> 2;          // 0..1
  const int colg = wave & 3;           // 0..3

  // XCD-aware swizzle: 8 XCDs x 40 m-tiles x 3 segs (960 % 8 == 0, bijective)
  const int bid   = blockIdx.x;
  const int xcd   = bid & 7;
  const int local = bid >> 3;          // 0..119
  const int seg   = local % 3;
  const int mt    = xcd * 40 + local / 3;
  const int m0    = mt * 128;

  // --- staging source pointers (per-lane, pre-swizzled k-octet) ---
  const __bf16 *gB0, *gB1, *gB2, *gB3;
  {
    int c, col, rk;
    c = wave * 256 + 0 * 64 + lane; col = c >> 2; rk = (c & 3) ^ ((col >> 1) & 3);
    gB0 = wct + (size_t)(seg * 512 + col) * K3n + rk * 8;
    c = wave * 256 + 1 * 64 + lane; col = c >> 2; rk = (c & 3) ^ ((col >> 1) & 3);
    gB1 = wct + (size_t)(seg * 512 + col) * K3n + rk * 8;
    c = wave * 256 + 2 * 64 + lane; col = c >> 2; rk = (c & 3) ^ ((col >> 1) & 3);
    gB2 = wct + (size_t)(seg * 512 + col) * K3n + rk * 8;
    c = wave * 256 + 3 * 64 + lane; col = c >> 2; rk = (c & 3) ^ ((col >> 1) & 3);
    gB3 = wct + (size_t)(seg * 512 + col) * K3n + rk * 8;
  }
  const __bf16* gA;
  {
    int c   = tid;                     // A chunk id (0..511), 1 per thread
    int row = c >> 2;
    int rk  = (c & 3) ^ ((row >> 1) & 3);
    int grow = m0 + row;
    int b = grow / Nn, n = grow - b * Nn;
    gA = xpad + (size_t)(b * NPn + n) * Dn + rk * 8;  // covers x rows n-1..n+1
  }

  // --- fixed LDS fragment element-offsets (buffer-relative) ---
  int fAo0, fAo1, fAo2, fAo3, fBo[8];
  {
    int row;
    row = rowg * 64 + 0 * 16 + l15; fAo0 = row * BKn + (quad ^ ((row >> 1) & 3)) * 8;
    row = rowg * 64 + 1 * 16 + l15; fAo1 = row * BKn + (quad ^ ((row >> 1) & 3)) * 8;
    row = rowg * 64 + 2 * 16 + l15; fAo2 = row * BKn + (quad ^ ((row >> 1) & 3)) * 8;
    row = rowg * 64 + 3 * 16 + l15; fAo3 = row * BKn + (quad ^ ((row >> 1) & 3)) * 8;
#pragma unroll
    for (int tc = 0; tc < 8; ++tc) {
      int col = colg * 128 + tc * 16 + l15;
      fBo[tc] = 4096 + col * BKn + (quad ^ ((col >> 1) & 3)) * 8;
    }
  }

  // --- staging LDS dest offsets (wave-uniform base; HW adds lane*16B) ---
  const int dA = wave * 512;               // A region: elements 0..4095
  const int dB = 4096 + wave * 2048;       // B region: elements 4096..20479

  floatx4 acc[4][8];
  const floatx4 zero = {0.f, 0.f, 0.f, 0.f};
#pragma unroll
  for (int i = 0; i < 4; ++i)
#pragma unroll
    for (int j = 0; j < 8; ++j) acc[i][j] = zero;

#define QKV_STAGE(NB) do {                                             \
    __bf16* _s = lds + (NB) * 20480;                                   \
    gload_lds16(gA,  _s + dA);          gA  += BKn;                    \
    gload_lds16(gB0, _s + dB);          gB0 += BKn;                    \
    gload_lds16(gB1, _s + dB + 512);    gB1 += BKn;                    \
    gload_lds16(gB2, _s + dB + 1024);   gB2 += BKn;                    \
    gload_lds16(gB3, _s + dB + 1536);   gB3 += BKn;                    \
  } while (0)

#define QKV_STEP(CB, NB, DOSTAGE, VMS) do {                            \
    if (DOSTAGE) QKV_STAGE(NB);                                        \
    const __bf16* _L = lds + (CB) * 20480;                             \
    bf16x8 _a0 = *(const bf16x8*)(_L + fAo0);                          \
    bf16x8 _a1 = *(const bf16x8*)(_L + fAo1);                          \
    bf16x8 _a2 = *(const bf16x8*)(_L + fAo2);                          \
    bf16x8 _a3 = *(const bf16x8*)(_L + fAo3);                          \
    __builtin_amdgcn_s_setprio(1);                                     \
    _Pragma("unroll")                                                  \
    for (int _n = 0; _n < 8; ++_n) {                                   \
      bf16x8 _b = *(const bf16x8*)(_L + fBo[_n]);                      \
      acc[0][_n] = __builtin_amdgcn_mfma_f32_16x16x32_bf16(_a0, _b, acc[0][_n], 0, 0, 0); \
      acc[1][_n] = __builtin_amdgcn_mfma_f32_16x16x32_bf16(_a1, _b, acc[1][_n], 0, 0, 0); \
      acc[2][_n] = __builtin_amdgcn_mfma_f32_16x16x32_bf16(_a2, _b, acc[2][_n], 0, 0, 0); \
      acc[3][_n] = __builtin_amdgcn_mfma_f32_16x16x32_bf16(_a3, _b, acc[3][_n], 0, 0, 0); \
    }                                                                  \
    __builtin_amdgcn_s_setprio(0);                                     \
    asm volatile("s_waitcnt vmcnt(" VMS ") lgkmcnt(0)\n\ts_barrier" ::: "memory"); \
  } while (0)

  // prologue: stage steps 0 and 1; wait for step-0 data (5 oldest of 10)
  QKV_STAGE(0);
  QKV_STAGE(1);
  asm volatile("s_waitcnt vmcnt(5)\n\ts_barrier" ::: "memory");

  // main loop: 48 K-steps; step t computes buf t%3, stages t+2 into (t+2)%3
#pragma unroll 1
  for (int it = 0; it < 15; ++it) {          // steps 0..44
    QKV_STEP(0, 2, true, "5");
    QKV_STEP(1, 0, true, "5");
    QKV_STEP(2, 1, true, "5");
  }
  QKV_STEP(0, 2, true, "5");                 // step 45 (stages step 47)
  QKV_STEP(1, 0, false, "0");                // step 46
  QKV_STEP(2, 0, false, "0");                // step 47

#undef QKV_STEP
#undef QKV_STAGE

  // --- fused LayerNorm + residual epilogue ---
  float s1[16], s2[16];
#pragma unroll
  for (int m = 0; m < 4; ++m)
#pragma unroll
    for (int r = 0; r < 4; ++r) {
      float a = 0.f, b2 = 0.f;
#pragma unroll
      for (int n = 0; n < 8; ++n) { float v = acc[m][n][r]; a += v; b2 += v * v; }
      s1[m * 4 + r] = a; s2[m * 4 + r] = b2;
    }
#pragma unroll
  for (int off = 1; off < 16; off <<= 1)
#pragma unroll
    for (int i = 0; i < 16; ++i) {
      s1[i] += __shfl_xor(s1[i], off, 64);
      s2[i] += __shfl_xor(s2[i], off, 64);
    }
  if (l15 == 0) {
#pragma unroll
    for (int i = 0; i < 16; ++i) {
      int m = i >> 2, r = i & 3;
      int row = rowg * 64 + m * 16 + quad * 4 + r;
      red1[row * 4 + colg] = s1[i];
      red2[row * 4 + colg] = s2[i];
    }
  }
  __syncthreads();

  const float* gg = (seg == 0) ? gq_g : ((seg == 1) ? gk_g : gv_g);
  const float* bb = (seg == 0) ? gq_b : ((seg == 1) ? gk_b : gv_b);
#pragma unroll
  for (int m = 0; m < 4; ++m)
#pragma unroll
    for (int r = 0; r < 4; ++r) {
      int row = rowg * 64 + m * 16 + quad * 4 + r;
      float su = red1[row * 4] + red1[row * 4 + 1] + red1[row * 4 + 2] + red1[row * 4 + 3];
      float sq = red2[row * 4] + red2[row * 4 + 1] + red2[row * 4 + 2] + red2[row * 4 + 3];
      float mn = su * (1.f / 512.f);
      float vv = sq * (1.f / 512.f) - mn * mn;
      float rstd = rsqrtf(vv + 1e-5f);
      int grow = m0 + row;
      int b = grow / Nn, n2 = grow - b * Nn;
      const __bf16* xr = xpad + (size_t)(b * NPn + n2 + 1) * Dn;  // bf16 residual (L2-hot)
#pragma unroll
      for (int n = 0; n < 8; ++n) {
        int col = colg * 128 + n * 16 + l15;
        float val = (acc[m][n][r] - mn) * rstd * gg[col] + bb[col] + (float)xr[col];
        qkv[(size_t)grow * K3n + seg * 512 + col] = (__bf16)val;
      }
    }
}

// ======== qfp = tanh(x @ Wqf + bqf) @ Wqp  (fused, fp32 out) ================
// Block: 64 rows x 64 cols, 256 thr = 4 waves, wave = 16 rows x 64 cols. K=512.
// Epilogue: per-row dot with Wqp via shfl reduction over l15 -> qfp[row][8].
__global__ __launch_bounds__(256)
void k_qfqp(const __bf16* __restrict__ xpad, const __bf16* __restrict__ wqft,
            const float* __restrict__ bqf, const float* __restrict__ wqp,
            float* __restrict__ qfp) {
  __shared__ __bf16 lA[64 * BKn];
  __shared__ __bf16 lB[64 * BKn];
  __shared__ float lWqpT[8 * 64];   // [h][col]
  const int tid  = threadIdx.x;
  const int wave = tid >> 6;
  const int lane = tid & 63;
  const int quad = lane >> 4;
  const int l15  = lane & 15;
  const int m0   = blockIdx.x * 64;

#pragma unroll
  for (int t = tid; t < 512; t += 256) {
    int col = t & 63, h = t >> 6;
    lWqpT[t] = wqp[col * 8 + h];
  }

  int c = wave * 64 + lane;
  int rowc = c >> 2;
  int rk   = (c & 3) ^ ((rowc >> 1) & 3);
  int grow = m0 + rowc;
  int b = grow / Nn, n = grow - b * Nn;
  const __bf16* gA = xpad + (size_t)(b * NPn + n + 1) * Dn + rk * 8;  // x[b][n]
  const __bf16* gB = wqft + (size_t)rowc * Dn + rk * 8;

  int frow = wave * 16 + l15;
  const __bf16* fA = lA + frow * BKn + (quad ^ ((frow >> 1) & 3)) * 8;
  const __bf16* fB[4];
#pragma unroll
  for (int tc = 0; tc < 4; ++tc) {
    int col = tc * 16 + l15;
    fB[tc] = lB + col * BKn + (quad ^ ((col >> 1) & 3)) * 8;
  }

  const floatx4 zero = {0.f, 0.f, 0.f, 0.f};
  floatx4 acc[4] = {zero, zero, zero, zero};

  for (int kt = 0; kt < Dn / BKn; ++kt) {
    gload_lds16(gA, lA + wave * 512);
    gload_lds16(gB, lB + wave * 512);
    __syncthreads();
    bf16x8 a = *(const bf16x8*)fA;
#pragma unroll
    for (int tc = 0; tc < 4; ++tc)
      acc[tc] = __builtin_amdgcn_mfma_f32_16x16x32_bf16(a, *(const bf16x8*)fB[tc], acc[tc], 0, 0, 0);
    __syncthreads();
    gA += BKn; gB += BKn;
  }

  // epilogue: t = tanh(acc + bqf); qfp[row][h] = sum_col t*WqpT[h][col]
  float part[4][8];
#pragma unroll
  for (int r = 0; r < 4; ++r)
#pragma unroll
    for (int h = 0; h < 8; ++h) part[r][h] = 0.f;
#pragma unroll
  for (int tc = 0; tc < 4; ++tc) {
    int col = tc * 16 + l15;
    float bq = bqf[col];
#pragma unroll
    for (int r = 0; r < 4; ++r) {
      float t = tanhf(acc[tc][r] + bq);
#pragma unroll
      for (int h = 0; h < 8; ++h) part[r][h] += t * lWqpT[h * 64 + col];
    }
  }
#pragma unroll
  for (int off = 1; off < 16; off <<= 1)
#pragma unroll
    for (int r = 0; r < 4; ++r)
#pragma unroll
      for (int h = 0; h < 8; ++h) part[r][h] += __shfl_xor(part[r][h], off, 64);
  if (l15 == 0) {
#pragma unroll
    for (int r = 0; r < 4; ++r) {
      int row = wave * 16 + quad * 4 + r;
#pragma unroll
      for (int h = 0; h < 8; ++h)
        qfp[(size_t)(m0 + row) * 8 + h] = part[r][h];
    }
  }
}

// =========================== attention (fp32) ===============================
// One wave per (b,h). scores = qk^T/8 + bias[h] + qfp_i - qfp_j; softmax; @v.
__global__ __launch_bounds__(256)
void k_attn(const __bf16* __restrict__ qkv, const float* __restrict__ qfp,
            const float* __restrict__ bias, __bf16* __restrict__ aout) {
  __shared__ float sq[4][Nn * 64];
  __shared__ float sk[4][Nn * 68];
  __shared__ float sv[4][Nn * 68];
  __shared__ float sp[4][Nn * Nn];
  __shared__ float sf[4][Nn];
  const int tid  = threadIdx.x;
  const int w    = tid >> 6;
  const int lane = tid & 63;
  const int p0 = blockIdx.x * 4 + w;
  const int b = p0 >> 3, h = p0 & 7;
  const __bf16* qb = qkv + (size_t)b * Nn * K3n + h * 64;

  // vectorized staging: 160 bf16x8 chunks per matrix
  for (int idx = lane; idx < 160; idx += 64) {
    int n = idx >> 3, c = (idx & 7) * 8;
    bf16x8 qv = *(const bf16x8*)(qb + (size_t)n * K3n + c);
    bf16x8 kv = *(const bf16x8*)(qb + (size_t)n * K3n + 512 + c);
    bf16x8 vv = *(const bf16x8*)(qb + (size_t)n * K3n + 1024 + c);
#pragma unroll
    for (int e = 0; e < 8; ++e) {
      sq[w][n * 64 + c + e] = (float)qv[e];
      sk[w][n * 68 + c + e] = (float)kv[e];
      sv[w][n * 68 + c + e] = (float)vv[e];
    }
  }
  if (lane < Nn) sf[w][lane] = qfp[(size_t)(b * Nn + lane) * 8 + h];
  __syncthreads();

  // scores: all 64 lanes over 400 (i,j) pairs
  const float* bh = bias + h * Nn * Nn;
  for (int p = lane; p < Nn * Nn; p += 64) {
    int i = p / Nn, j = p - i * Nn;
    const float4* q4 = (const float4*)&sq[w][i * 64];
    const float4* k4 = (const float4*)&sk[w][j * 68];
    float s = 0.f;
#pragma unroll
    for (int d4 = 0; d4 < 16; ++d4) {
      float4 qa = q4[d4], ka = k4[d4];
      s += qa.x * ka.x + qa.y * ka.y + qa.z * ka.z + qa.w * ka.w;
    }
    sp[w][p] = s * 0.125f + bh[p] + sf[w][i] - sf[w][j];
  }
  __syncthreads();
  if (lane < Nn) {
    int i = lane;
    float* row = &sp[w][i * Nn];
    float mx = row[0];
    for (int j = 1; j < Nn; ++j) mx = fmaxf(mx, row[j]);
    float sum = 0.f;
    for (int j = 0; j < Nn; ++j) { float e = __expf(row[j] - mx); row[j] = e; sum += e; }
    float inv = 1.f / sum;
    for (int j = 0; j < Nn; ++j) row[j] *= inv;
  }
  __syncthreads();
  for (int i = 0; i < Nn; ++i) {
    float a = 0.f;
#pragma unroll
    for (int j = 0; j < Nn; ++j) a += sp[w][i * Nn + j] * sv[w][j * 68 + lane];
    aout[(size_t)(b * Nn + i) * Dn + h * 64 + lane] = (__bf16)a;
  }
}

// ==================== out = attn_out @ Wo + bo (fp32 out) ===================
__global__ __launch_bounds__(512)
void k_oproj(const __bf16* __restrict__ aout, const __bf16* __restrict__ wot,
             const float* __restrict__ bo, float* __restrict__ out) {
  __shared__ __bf16 lA[64 * BKn];
  __shared__ __bf16 lB[512 * BKn];
  const int tid  = threadIdx.x;
  const int wave = tid >> 6;
  const int lane = tid & 63;
  const int quad = lane >> 4;
  const int l15  = lane & 15;
  const int rowg = wave >> 2;
  const int colg = wave & 3;
  const int m0   = blockIdx.x * 64;

  const __bf16* gB[4];
#pragma unroll
  for (int t = 0; t < 4; ++t) {
    int c   = wave * 256 + t * 64 + lane;
    int col = c >> 2;
    int rk  = (c & 3) ^ ((col >> 1) & 3);
    gB[t] = wot + (size_t)col * Dn + rk * 8;
  }
  const __bf16* gA;
  {
    int c   = (wave & 3) * 64 + lane;
    int row = c >> 2;
    int rk  = (c & 3) ^ ((row >> 1) & 3);
    gA = aout + (size_t)(m0 + row) * Dn + rk * 8;
  }
  const __bf16* fA[2];
#pragma unroll
  for (int tr = 0; tr < 2; ++tr) {
    int row = rowg * 32 + tr * 16 + l15;
    fA[tr] = lA + row * BKn + (quad ^ ((row >> 1) & 3)) * 8;
  }
  const __bf16* fB[8];
#pragma unroll
  for (int tc = 0; tc < 8; ++tc) {
    int col = colg * 128 + tc * 16 + l15;
    fB[tc] = lB + col * BKn + (quad ^ ((col >> 1) & 3)) * 8;
  }

  const floatx4 zero = {0.f, 0.f, 0.f, 0.f};
  floatx4 acc[2][8];
#pragma unroll
  for (int i = 0; i < 2; ++i)
#pragma unroll
    for (int j = 0; j < 8; ++j) acc[i][j] = zero;

  __bf16* dstB = lB + wave * 2048;
  __bf16* dstA = lA + (wave & 3) * 512;

  for (int kt = 0; kt < Dn / BKn; ++kt) {
#pragma unroll
    for (int t = 0; t < 4; ++t) gload_lds16(gB[t], dstB + t * 512);
    if (wave < 4) gload_lds16(gA, dstA);
    __syncthreads();
    bf16x8 a0 = *(const bf16x8*)fA[0];
    bf16x8 a1 = *(const bf16x8*)fA[1];
#pragma unroll
    for (int tc = 0; tc < 8; ++tc) {
      bf16x8 b0 = *(const bf16x8*)fB[tc];
      acc[0][tc] = __builtin_amdgcn_mfma_f32_16x16x32_bf16(a0, b0, acc[0][tc], 0, 0, 0);
      acc[1][tc] = __builtin_amdgcn_mfma_f32_16x16x32_bf16(a1, b0, acc[1][tc], 0, 0, 0);
    }
    __syncthreads();
#pragma unroll
    for (int t = 0; t < 4; ++t) gB[t] += BKn;
    gA += BKn;
  }
#pragma unroll
  for (int tr = 0; tr < 2; ++tr)
#pragma unroll
    for (int r = 0; r < 4; ++r) {
      int row = rowg * 32 + tr * 16 + quad * 4 + r;
#pragma unroll
      for (int tc = 0; tc < 8; ++tc) {
        int col = colg * 128 + tc * 16 + l15;
        out[(size_t)(m0 + row) * Dn + col] = acc[tr][tc][r] + bo[col];
      }
    }
}

// ============================ workspace layout ==============================
static const size_t OFF_XPAD = 0;                     // 46,137,344 B (bf16 Xpad)
static const size_t OFF_WCT  = 46137344;              //  4,718,592 B
static const size_t OFF_WOT  = 50855936;              //    524,288 B
static const size_t OFF_WQFT = 51380224;              //     65,536 B
static const size_t OFF_QKV  = 51445760;              // 125,829,120 B
static const size_t OFF_QFP  = 177274880;             //  1,310,720 B
static const size_t OFF_BIAS = 178585600;             //     12,800 B
static const size_t OFF_AOUT = 0;                     // overlays Xpad (dead after k_qfqp/k_qkv)

extern "C" void kernel_launch(void* const* d_in, const int* in_sizes, int n_in,
                              void* d_out, int out_size, void* d_ws, size_t ws_size,
                              hipStream_t stream) {
  (void)in_sizes; (void)n_in; (void)out_size; (void)ws_size;
  const float* x     = (const float*)d_in[0];
  const float* Wq    = (const float*)d_in[1];
  const float* Wk    = (const float*)d_in[2];
  const float* Wv    = (const float*)d_in[3];
  const float* gq_g  = (const float*)d_in[4];
  const float* gq_b  = (const float*)d_in[5];
  const float* gk_g  = (const float*)d_in[6];
  const float* gk_b  = (const float*)d_in[7];
  const float* gv_g  = (const float*)d_in[8];
  const float* gv_b  = (const float*)d_in[9];
  const float* rel   = (const float*)d_in[10];
  const float* gsb   = (const float*)d_in[11];
  const float* alpha = (const float*)d_in[12];
  const float* Wqf   = (const float*)d_in[13];
  const float* bqf   = (const float*)d_in[14];
  const float* Wqp   = (const float*)d_in[15];
  const float* bqp   = (const float*)d_in[16];
  const float* Wo    = (const float*)d_in[17];
  const float* bo    = (const float*)d_in[18];
  float* out = (float*)d_out;
  char* ws = (char*)d_ws;

  __bf16* xpad = (__bf16*)(ws + OFF_XPAD);
  __bf16* wct  = (__bf16*)(ws + OFF_WCT);
  __bf16* wot  = (__bf16*)(ws + OFF_WOT);
  __bf16* wqft = (__bf16*)(ws + OFF_WQFT);
  __bf16* qkv  = (__bf16*)(ws + OFF_QKV);
  float*  qfp  = (float*)(ws + OFF_QFP);
  float*  bias = (float*)(ws + OFF_BIAS);
  __bf16* aout = (__bf16*)(ws + OFF_AOUT);

  k_prep_xpad<<<(Bn * NPn * (Dn / 8) + 255) / 256, 256, 0, stream>>>(x, xpad);
  k_prep_wct <<<(K3n * K3n + 255) / 256, 256, 0, stream>>>(Wq, Wk, Wv, wct);
  k_prep_wot <<<(Dn * Dn + 255) / 256, 256, 0, stream>>>(Wo, wot);
  k_prep_wqft<<<(Dn * 64 + 255) / 256, 256, 0, stream>>>(Wqf, wqft);
  k_bias     <<<(Hn * Nn * Nn + 255) / 256, 256, 0, stream>>>(rel, gsb, alpha, bqp, bias);

  k_qkv <<<Mn / 128 * 3, 512, 0, stream>>>(xpad, wct, gq_g, gq_b, gk_g, gk_b, gv_g, gv_b, qkv);
  k_qfqp<<<Mn / 64, 256, 0, stream>>>(xpad, wqft, bqf, Wqp, qfp);
  k_attn<<<(Bn * Hn) / 4, 256, 0, stream>>>(qkv, qfp, bias, aout);
  k_oproj<<<Mn / 64, 512, 0, stream>>>(aout, wot, bo, out);
}